// Round 2
// baseline (166.211 us; speedup 1.0000x reference)
//
#include <hip/hip_runtime.h>

// Adaptive max pool NHWC (128,57,57,512) f32 -> (128,7,7,512) f32.
// Bins: [8,8,8,8,8,8,9] in both H and W (offsets 0,8,...,48,57).
// Strip version: one block per (n, oh); 256 threads = 2 half-groups of 128.
// Each half streams complete contiguous rows (57*512*4 = 116,736 B each) and
// keeps 7 per-ow-bin float4 accumulators (all statically indexed). Halves
// merge via LDS, half 0 writes the 7 outputs.

#define N_   128
#define H_   57
#define W_   57
#define C_   512
#define OH_  7
#define OW_  7
#define C4_  (C_ / 4)   // 128 float4 lanes per spatial position

__global__ __launch_bounds__(256)
void adaptive_maxpool_strip(const float* __restrict__ x, float* __restrict__ out) {
    const int bid = blockIdx.x;            // n*7 + oh
    const int oh  = bid % OH_;
    const int n   = bid / OH_;
    const int c4  = threadIdx.x & (C4_ - 1);   // 0..127
    const int g   = threadIdx.x >> 7;          // half-group 0/1

    const int h0  = oh * 8;
    const int h1  = (oh == OH_ - 1) ? H_ : h0 + 8;
    // half 0: rows [h0, h0+4); half 1: rows [h0+4, h1) (4 or 5 rows)
    const int rh0 = g ? (h0 + 4) : h0;
    const int rh1 = g ? h1 : (h0 + 4);

    const float4* __restrict__ base =
        reinterpret_cast<const float4*>(x) + (size_t)n * H_ * W_ * C4_ + c4;

    const float4 ninf = make_float4(-INFINITY, -INFINITY, -INFINITY, -INFINITY);
    float4 acc[OW_];
    #pragma unroll
    for (int wb = 0; wb < OW_; ++wb) acc[wb] = ninf;

    for (int h = rh0; h < rh1; ++h) {
        const float4* __restrict__ row = base + (size_t)h * W_ * C4_;
        #pragma unroll
        for (int wb = 0; wb < OW_; ++wb) {          // static accumulator index
            const int wcnt = (wb == OW_ - 1) ? 9 : 8;
            #pragma unroll
            for (int ww = 0; ww < 9; ++ww) {
                if (ww < wcnt) {
                    float4 v = row[(size_t)(wb * 8 + ww) * C4_];
                    acc[wb].x = fmaxf(acc[wb].x, v.x);
                    acc[wb].y = fmaxf(acc[wb].y, v.y);
                    acc[wb].z = fmaxf(acc[wb].z, v.z);
                    acc[wb].w = fmaxf(acc[wb].w, v.w);
                }
            }
        }
    }

    // Merge the two halves through LDS (14,336 B).
    __shared__ float4 lds[OW_][C4_];
    if (g == 1) {
        #pragma unroll
        for (int wb = 0; wb < OW_; ++wb) lds[wb][c4] = acc[wb];
    }
    __syncthreads();
    if (g == 0) {
        float4* __restrict__ o =
            reinterpret_cast<float4*>(out) + (size_t)bid * OW_ * C4_ + c4;
        #pragma unroll
        for (int wb = 0; wb < OW_; ++wb) {
            float4 p = lds[wb][c4];
            float4 r;
            r.x = fmaxf(acc[wb].x, p.x);
            r.y = fmaxf(acc[wb].y, p.y);
            r.z = fmaxf(acc[wb].z, p.z);
            r.w = fmaxf(acc[wb].w, p.w);
            o[(size_t)wb * C4_] = r;
        }
    }
}

extern "C" void kernel_launch(void* const* d_in, const int* in_sizes, int n_in,
                              void* d_out, int out_size, void* d_ws, size_t ws_size,
                              hipStream_t stream) {
    const float* x = (const float*)d_in[0];
    float* out = (float*)d_out;
    const int grid = N_ * OH_;   // 896 blocks
    adaptive_maxpool_strip<<<grid, 256, 0, stream>>>(x, out);
}

// Round 4
// 139.889 us; speedup vs baseline: 1.1882x; 1.1882x over previous
//
#include <hip/hip_runtime.h>

// Adaptive max pool NHWC (128,57,57,512) f32 -> (128,7,7,512) f32.
// Bins: [8,8,8,8,8,8,9] in H and W. Disjoint bins => exact-once read, pure
// HBM streaming (851 MB in, 12.9 MB out). Round-4: round-1 structure
// (1 block per output position, 128 threads = C as float4) + nontemporal
// loads via native ext_vector type (HIP float4 class is rejected by the
// builtin) + fully static unrolled bodies per bin shape.

#define N_   128
#define H_   57
#define W_   57
#define C_   512
#define OH_  7
#define OW_  7
#define C4_  (C_ / 4)   // 128 float4 per spatial position

typedef float f4 __attribute__((ext_vector_type(4)));

template <int HCNT, int WCNT>
__device__ __forceinline__ f4 pool_body(const f4* __restrict__ base) {
    f4 m = { -INFINITY, -INFINITY, -INFINITY, -INFINITY };
    #pragma unroll
    for (int hh = 0; hh < HCNT; ++hh) {
        #pragma unroll
        for (int ww = 0; ww < WCNT; ++ww) {
            f4 v = __builtin_nontemporal_load(base + ((size_t)hh * W_ + ww) * C4_);
            m.x = fmaxf(m.x, v.x);
            m.y = fmaxf(m.y, v.y);
            m.z = fmaxf(m.z, v.z);
            m.w = fmaxf(m.w, v.w);
        }
    }
    return m;
}

__global__ __launch_bounds__(128)
void adaptive_maxpool_kernel(const float* __restrict__ x, float* __restrict__ out) {
    const int bid = blockIdx.x;
    const int ow  = bid % OW_;
    const int oh  = (bid / OW_) % OH_;
    const int n   = bid / (OW_ * OH_);
    const int c4  = threadIdx.x;           // 0..127

    const int h0 = oh * 8;
    const int w0 = ow * 8;

    const f4* __restrict__ base =
        reinterpret_cast<const f4*>(x) +
        (size_t)n * H_ * W_ * C4_ + (size_t)h0 * W_ * C4_ + (size_t)w0 * C4_ + c4;

    // Wave-uniform branch into fully-static bodies.
    f4 m;
    const bool hl = (oh == OH_ - 1);
    const bool wl = (ow == OW_ - 1);
    if (!hl && !wl)      m = pool_body<8, 8>(base);
    else if (!hl)        m = pool_body<8, 9>(base);
    else if (!wl)        m = pool_body<9, 8>(base);
    else                 m = pool_body<9, 9>(base);

    f4* o = reinterpret_cast<f4*>(out) + (size_t)bid * C4_ + c4;
    __builtin_nontemporal_store(m, o);
}

extern "C" void kernel_launch(void* const* d_in, const int* in_sizes, int n_in,
                              void* d_out, int out_size, void* d_ws, size_t ws_size,
                              hipStream_t stream) {
    const float* x = (const float*)d_in[0];
    float* out = (float*)d_out;
    const int grid = N_ * OH_ * OW_;   // 6272 blocks
    adaptive_maxpool_kernel<<<grid, 128, 0, stream>>>(x, out);
}